// Round 2
// baseline (188.436 us; speedup 1.0000x reference)
//
#include <hip/hip_runtime.h>

// CRF loss on MI355X — 2 batches per wave.
// B=512, L=512, T=32, S=34. Inputs: wtv f32[512,512,32], trans f32[34,34],
// rtag i32[512,512]. Output f32[512].
//
// Linear-domain forward algorithm with exact power-of-2 rescaling every 8
// steps. Latency-bound regime (serial 256-step recursion; per-step LDS
// all-to-all round-trip dominates), so each wave runs FOUR 16-lane
// chains (2 states per lane): q0 = batch b0 fwd, q1 = b0 bwd, q2 = b1 fwd,
// q3 = b1 bwd. The fixed per-step round-trip (write -> barrier -> 8x
// ds_read_b128 -> FMA chain) is amortized over 2 batches. Chains are offset
// by 36 floats in LDS (144 B: 16B-aligned, +4 bank offset per quad) so the
// quad-broadcast float4 reads stay conflict-free.
//
// Gold tags live in LDS (1024 ints), read per-step (prefetched 8-ahead),
// replacing the readlane + periodic reload machinery.

#define F2  1.4426950408889634f   // log2(e)
#define LN2 0.6931471805599453f

__global__ __launch_bounds__(64) void crf_kernel(
    const float* __restrict__ wtv,    // [512,512,32]
    const float* __restrict__ trans,  // [34,34]
    const int*   __restrict__ rtag,   // [512,512]
    float* __restrict__ out)          // [512]
{
    __shared__ __align__(16) float tlds[1156];  // raw translation (ln domain)
    __shared__ __align__(16) int   ltag[1024];  // gold tags for the 2 batches
    __shared__ __align__(16) float alds[144];   // 4 chains * 36 floats

    const int l  = threadIdx.x;
    const int q  = l >> 4;          // chain: 0=b0 fwd, 1=b0 bwd, 2=b1 fwd, 3=b1 bwd
    const int c4 = l & 15;
    const int h  = q & 1;           // 0 = forward, 1 = backward
    const int bp = q >> 1;          // batch within pair
    const int sA = 2 * c4;          // this lane's two states (0-based cols)
    const int sB = 2 * c4 + 1;

    const int bbase = blockIdx.x * 2;

    for (int k = l; k < 1156; k += 64) tlds[k] = trans[k];
    {
        const int* rb = rtag + (size_t)bbase * 512;
        for (int k = l; k < 1024; k += 64) ltag[k] = rb[k];
    }
    __syncthreads();  // once, before the main loop (graph-safe)

    // exp2-domain transition columns (fwd) / rows (bwd) for this lane's 2 states
    float tcA[32], tcB[32];
    #pragma unroll
    for (int k = 0; k < 32; ++k) {
        float tvA = h ? tlds[(sA + 1) * 34 + (k + 1)] : tlds[(k + 1) * 34 + (sA + 1)];
        float tvB = h ? tlds[(sB + 1) * 34 + (k + 1)] : tlds[(k + 1) * 34 + (sB + 1)];
        tcA[k] = __builtin_exp2f(F2 * tvA);
        tcB[k] = __builtin_exp2f(F2 * tvB);
    }
    float aiA = h ? 0.0f : __builtin_exp2f(F2 * tlds[sA + 1]);  // expT[0][s+1] at i==1
    float aiB = h ? 0.0f : __builtin_exp2f(F2 * tlds[sB + 1]);

    const float* wb  = wtv + (size_t)(bbase + bp) * (512 * 32);
    const float* wbl = wb + sA;

    int tag0 = ltag[bp << 9];

    float2 v0 = make_float2(0.0f, 0.0f);
    if (!h) v0 = *(const float2*)(wbl);                     // row 0 emissions
    float stA = h ? 1.0f : __builtin_exp2f(F2 * v0.x);      // alpha_0 / b_511
    float stB = h ? 1.0f : __builtin_exp2f(F2 * v0.y);
    float pathE = 0.0f;
    if (!h) {
        if (sA == tag0 - 1) pathE += v0.x;                  // t=0 gold emission
        if (sB == tag0 - 1) pathE += v0.y;
    }
    float pathT   = h ? 0.0f : tlds[tag0];                  // start term trans[0][tag_0]
    int   prevtag = h ? 33 : tag0;                          // bwd sentinel -> end term at i==1
    int   scaleE  = 0;

    // emission prefetch: iteration i reads row i (fwd) / row 512-i (bwd), float2/lane
    const int rs = h ? -16 : 16;    // row stride in float2 units
    float2 vn[8], vc[8], eo[8];
    {
        const float2* p = (const float2*)(wbl + (h ? 511 * 32 : 32));
        #pragma unroll
        for (int j = 0; j < 8; ++j) vn[j] = p[j * rs];
    }

    float*        ach = alds + q * 36;                 // chain base (16B aligned, +4 banks/quad)
    const float4* a4  = (const float4*)ach;
    float2*       wp  = (float2*)(ach + sA);

    for (int t0 = 1; t0 <= 249; t0 += 8) {   // 32 blocks, iterations i = 1..256
        #pragma unroll
        for (int j = 0; j < 8; ++j) {
            vc[j] = vn[j];
            eo[j].x = __builtin_exp2f(F2 * vc[j].x);
            eo[j].y = __builtin_exp2f(F2 * vc[j].y);
        }
        {   // prefetch next block (rows stay in [248..264] at the tail: in-bounds)
            int i8 = t0 + 8;
            int row8 = h ? (512 - i8) : i8;
            const float2* p = (const float2*)(wb + row8 * 32 + sA);
            #pragma unroll
            for (int j = 0; j < 8; ++j) vn[j] = p[j * rs];
        }
        int cts[8];  // gold tags for this block, off the critical path
        #pragma unroll
        for (int j = 0; j < 8; ++j) {
            int i = t0 + j;
            cts[j] = ltag[(bp << 9) + (h ? (512 - i) : i)];
        }
        #pragma unroll
        for (int j = 0; j < 8; ++j) {
            const int i = t0 + j;

            // publish state: fwd writes alpha, bwd writes g = eo*b (float2 = b64)
            float2 wv;
            wv.x = h ? stA * eo[j].x : stA;
            wv.y = h ? stB * eo[j].y : stB;
            *wp = wv;
            __builtin_amdgcn_wave_barrier();
            // broadcast-read own chain's 32 values (4 distinct bank-disjoint addrs/instr)
            float a0A = aiA, a1A = 0.0f, a2A = 0.0f, a3A = 0.0f;
            float a0B = aiB, a1B = 0.0f, a2B = 0.0f, a3B = 0.0f;
            aiA = 0.0f; aiB = 0.0f;
            #pragma unroll
            for (int k = 0; k < 8; ++k) {
                float4 x = a4[k];
                a0A += x.x * tcA[4 * k + 0]; a1A += x.y * tcA[4 * k + 1];
                a2A += x.z * tcA[4 * k + 2]; a3A += x.w * tcA[4 * k + 3];
                a0B += x.x * tcB[4 * k + 0]; a1B += x.y * tcB[4 * k + 1];
                a2B += x.z * tcB[4 * k + 2]; a3B += x.w * tcB[4 * k + 3];
            }
            __builtin_amdgcn_wave_barrier();
            float sAv = (a0A + a1A) + (a2A + a3A);
            float sBv = (a0B + a1B) + (a2B + a3B);
            float nsA = h ? sAv : sAv * eo[j].x;
            float nsB = h ? sBv : sBv * eo[j].y;

            bool doUpd = (i != 256) || (h == 0);  // i==256 is the fwd-only tail step
            stA = doUpd ? nsA : stA;
            stB = doUpd ? nsB : stB;

            // gold-path score
            int ct = cts[j];
            if (doUpd) {
                if (sA == ct - 1) pathE += vc[j].x;
                if (sB == ct - 1) pathE += vc[j].y;
            }
            int idx = h ? (ct * 34 + prevtag)    // bwd: trans[tag_u][tag_{u+1}]; i==1 -> end term
                        : (prevtag * 34 + ct);   // fwd: trans[tag_{i-1}][tag_i]
            float tvv = tlds[idx];
            pathT += doUpd ? tvv : 0.0f;
            if (!h || (i != 256)) prevtag = ct;
        }
        // exact power-of-2 rescale (per 16-lane chain)
        float m = fmaxf(stA, stB);
        m = fmaxf(m, __shfl_xor(m, 1));
        m = fmaxf(m, __shfl_xor(m, 2));
        m = fmaxf(m, __shfl_xor(m, 4));
        m = fmaxf(m, __shfl_xor(m, 8));
        int e = ((__float_as_int(m) >> 23) & 0xff) - 127;
        float sc = __int_as_float((127 - e) << 23);
        stA *= sc; stB *= sc;
        scaleE += e;
    }

    // ---- epilogue: Z = sum_c af_256[c] * b_256[c] (partner chain = xor 16) ----
    float boA = __shfl_xor(stA, 16);
    float boB = __shfl_xor(stB, 16);
    float prod = stA * boA + stB * boB;
    prod += __shfl_xor(prod, 1);
    prod += __shfl_xor(prod, 2);
    prod += __shfl_xor(prod, 4);
    prod += __shfl_xor(prod, 8);
    int scTot = scaleE + __shfl_xor(scaleE, 16);
    float total = ((float)scTot + __builtin_log2f(prod)) * LN2;

    pathE += __shfl_xor(pathE, 1);
    pathE += __shfl_xor(pathE, 2);
    pathE += __shfl_xor(pathE, 4);
    pathE += __shfl_xor(pathE, 8);
    pathE += __shfl_xor(pathE, 16);
    // prevtag(fwd) = tag_256, partner's prevtag = tag_257: the uncovered transition
    int otag = __shfl_xor(prevtag, 16);
    float pT = pathT + __shfl_xor(pathT, 16) + tlds[prevtag * 34 + otag];

    if (!h && c4 == 0) out[bbase + bp] = total - (pathE + pT);
}

extern "C" void kernel_launch(void* const* d_in, const int* in_sizes, int n_in,
                              void* d_out, int out_size, void* d_ws, size_t ws_size,
                              hipStream_t stream) {
    const float* wtv   = (const float*)d_in[0];
    const float* trans = (const float*)d_in[1];
    const int*   rtag  = (const int*)d_in[2];
    (void)in_sizes; (void)n_in; (void)d_ws; (void)ws_size; (void)out_size;
    float* out = (float*)d_out;
    crf_kernel<<<256, 64, 0, stream>>>(wtv, trans, rtag, out);
}

// Round 3
// 144.932 us; speedup vs baseline: 1.3002x; 1.3002x over previous
//
#include <hip/hip_runtime.h>

// CRF loss on MI355X — staggered 2-phase pipeline, 2 batches per wave.
// B=512, L=512, T=32, S=34. Inputs: wtv f32[512,512,32], trans f32[34,34],
// rtag i32[512,512]. Output f32[512].
//
// Linear-domain forward algorithm. Wave = 2 batches: lanes 0-31 = batch b0,
// lanes 32-63 = b1; each lane owns one state (c = lane&31). Per step i, two
// half-step slots:
//   slot O: publish bwd g_i + issue bwd reads  | fwd FMA (reads issued last slot)
//   slot E: publish fwd alpha_i + issue fwd reads | bwd FMA
// Each chain's ~120-cycle LDS read latency is covered by the partner
// chain-pair's FMA issue (~100 cyc) -> latency off the serial path.
//
// Exact 2^-7 bias folded into tc/aiF (power-of-2 multiply: mantissa-exact)
// lets the exact power-of-2 rescale run every 16 steps; corrected by
// BIASCNT = 7*(256 fwd + 255 bwd) at the end. Gold-path score computed in a
// gather epilogue (L2/L3-warm), fully removed from the serial loop.

#define F2   1.4426950408889634f   // log2(e)
#define LN2  0.6931471805599453f
#define BIAS 0.0078125f            // 2^-7, exact
#define BIASCNT 3577               // 7 * 511 applications of biased tc

__global__ __launch_bounds__(64) void crf_kernel(
    const float* __restrict__ wtv,    // [512,512,32]
    const float* __restrict__ trans,  // [34,34]
    const int*   __restrict__ rtag,   // [512,512]
    float* __restrict__ out)          // [512]
{
    __shared__ __align__(16) float tlds[1156];  // raw translation (ln domain)
    __shared__ __align__(16) int   ltag[1024];  // gold tags, 2 batches
    __shared__ __align__(16) float alds[160];   // F: q*36 + [0..31]; B: 80 + q*36 + [0..31]

    const int l = threadIdx.x;
    const int q = l >> 5;        // batch within pair
    const int c = l & 31;        // state-1
    const int bbase = blockIdx.x * 2;

    for (int k = l; k < 1156; k += 64) tlds[k] = trans[k];
    {
        const int* rtb = rtag + (size_t)bbase * 512;
        for (int k = l; k < 1024; k += 64) ltag[k] = rtb[k];
    }
    __syncthreads();  // once, before the main loop (graph-safe)

    // exp2-domain transitions, exact 2^-7 bias folded in
    float tcF[32], tcB[32];
    #pragma unroll
    for (int k = 0; k < 32; ++k) {
        tcF[k] = __builtin_exp2f(F2 * tlds[(k + 1) * 34 + (c + 1)]) * BIAS; // col c+1
        tcB[k] = __builtin_exp2f(F2 * tlds[(c + 1) * 34 + (k + 1)]) * BIAS; // row c+1
    }
    float aiF = __builtin_exp2f(F2 * tlds[c + 1]) * BIAS;  // START term, step 1 only

    const float* wbq = wtv + (size_t)(bbase + q) * (512 * 32);

    float stF = __builtin_exp2f(F2 * wbq[c]);   // alpha_0 (row-0 emission)
    float stB = 1.0f;                           // b_511
    int scF = 0, scB = 0;

    // emission double-buffer: vn holds next block's raw values
    float vnF[8], vnB[8], eoF[8], eoB[8];
    #pragma unroll
    for (int j = 0; j < 8; ++j) {
        vnF[j] = wbq[(1 + j) * 32 + c];        // rows 1..8
        vnB[j] = wbq[(511 - j) * 32 + c];      // rows 511..504
    }

    float* aF = alds + q * 36;          // fwd region (16B-aligned, +4 banks/half)
    float* aB = alds + 80 + q * 36;     // bwd region
    const float4* f4 = (const float4*)aF;
    const float4* b4 = (const float4*)aB;

    float4 ra[8], rb[8];

    // ---- prologue: publish alpha_0, issue fwd reads ----
    aF[c] = stF;
    __builtin_amdgcn_wave_barrier();
    #pragma unroll
    for (int k = 0; k < 8; ++k) ra[k] = f4[k];
    __builtin_amdgcn_wave_barrier();

    for (int t0 = 1; t0 <= 249; t0 += 8) {   // 32 blocks, steps i = 1..256
        #pragma unroll
        for (int j = 0; j < 8; ++j) {
            eoF[j] = __builtin_exp2f(F2 * vnF[j]);
            eoB[j] = __builtin_exp2f(F2 * vnB[j]);
        }
        {   // prefetch next block's emissions (tail rows 257/255: in-bounds)
            const int i8 = t0 + 8;
            #pragma unroll
            for (int j = 0; j < 8; ++j) {
                vnF[j] = wbq[(i8 + j) * 32 + c];
                vnB[j] = wbq[(512 - i8 - j) * 32 + c];
            }
        }
        const bool resc = ((t0 + 7) & 15) == 0;   // every 16 steps
        #pragma unroll
        for (int j = 0; j < 8; ++j) {
            const int i = t0 + j;

            // ---- SLOT O: publish bwd g_i, issue bwd reads | fwd FMA step i ----
            aB[c] = stB * eoB[j];
            __builtin_amdgcn_wave_barrier();
            #pragma unroll
            for (int k = 0; k < 8; ++k) rb[k] = b4[k];
            __builtin_amdgcn_wave_barrier();
            {
                float a0 = aiF, a1 = 0.0f, a2 = 0.0f, a3 = 0.0f;
                aiF = 0.0f;
                #pragma unroll
                for (int k = 0; k < 8; ++k) {
                    float4 x = ra[k];
                    a0 += x.x * tcF[4 * k + 0]; a1 += x.y * tcF[4 * k + 1];
                    a2 += x.z * tcF[4 * k + 2]; a3 += x.w * tcF[4 * k + 3];
                }
                float s = (a0 + a1) + (a2 + a3);
                stF = s * eoF[j];                 // fwd updates at all i = 1..256
            }
            if (j == 7 && resc) {
                // fwd rescale between update and publish; overlaps slot E's bwd FMA
                float m = stF;
                m = fmaxf(m, __shfl_xor(m, 1));
                m = fmaxf(m, __shfl_xor(m, 2));
                m = fmaxf(m, __shfl_xor(m, 4));
                m = fmaxf(m, __shfl_xor(m, 8));
                m = fmaxf(m, __shfl_xor(m, 16));
                int e = ((__float_as_int(m) >> 23) & 0xff) - 127;
                stF *= __int_as_float((127 - e) << 23);
                scF += e;
            }

            // ---- SLOT E: publish fwd alpha_i, issue fwd reads | bwd FMA step i ----
            aF[c] = stF;
            __builtin_amdgcn_wave_barrier();
            #pragma unroll
            for (int k = 0; k < 8; ++k) ra[k] = f4[k];
            __builtin_amdgcn_wave_barrier();
            {
                float a0 = 0.0f, a1 = 0.0f, a2 = 0.0f, a3 = 0.0f;
                #pragma unroll
                for (int k = 0; k < 8; ++k) {
                    float4 x = rb[k];
                    a0 += x.x * tcB[4 * k + 0]; a1 += x.y * tcB[4 * k + 1];
                    a2 += x.z * tcB[4 * k + 2]; a3 += x.w * tcB[4 * k + 3];
                }
                float s = (a0 + a1) + (a2 + a3);
                stB = (i != 256) ? s : stB;       // i==256 is the fwd-only tail step
            }
        }
        if (resc) {
            // bwd rescale at block boundary (before its next publish)
            float m = stB;
            m = fmaxf(m, __shfl_xor(m, 1));
            m = fmaxf(m, __shfl_xor(m, 2));
            m = fmaxf(m, __shfl_xor(m, 4));
            m = fmaxf(m, __shfl_xor(m, 8));
            m = fmaxf(m, __shfl_xor(m, 16));
            int e = ((__float_as_int(m) >> 23) & 0xff) - 127;
            stB *= __int_as_float((127 - e) << 23);
            scB += e;
        }
    }

    // ---- Z = sum_c af_256[c] * b_256[c], per 32-lane half ----
    float prod = stF * stB;
    prod += __shfl_xor(prod, 1);
    prod += __shfl_xor(prod, 2);
    prod += __shfl_xor(prod, 4);
    prod += __shfl_xor(prod, 8);
    prod += __shfl_xor(prod, 16);
    float total = ((float)(scF + scB + BIASCNT) + __builtin_log2f(prod)) * LN2;

    // ---- gold-path score epilogue: all 64 lanes per batch, gathers L2/L3-warm ----
    float ps0 = 0.0f, ps1 = 0.0f;
    #pragma unroll
    for (int bb = 0; bb < 2; ++bb) {
        const float* w  = wtv + (size_t)(bbase + bb) * (512 * 32);
        const int*   tg = ltag + (bb << 9);
        int   tcur[8];
        float em[8];
        #pragma unroll
        for (int k = 0; k < 8; ++k) tcur[k] = tg[l + 64 * k];
        #pragma unroll
        for (int k = 0; k < 8; ++k) em[k] = w[(l + 64 * k) * 32 + (tcur[k] - 1)];
        float acc = 0.0f;
        #pragma unroll
        for (int k = 0; k < 8; ++k) {
            int t  = l + 64 * k;
            int nx = tg[(t + 1) & 511];
            nx = (t == 511) ? 33 : nx;            // end term trans[tag_511][STOP]
            acc += em[k] + tlds[tcur[k] * 34 + nx];
        }
        if (l == 0) acc += tlds[tg[0]];           // start term trans[0][tag_0]
        acc += __shfl_xor(acc, 1);
        acc += __shfl_xor(acc, 2);
        acc += __shfl_xor(acc, 4);
        acc += __shfl_xor(acc, 8);
        acc += __shfl_xor(acc, 16);
        acc += __shfl_xor(acc, 32);
        if (bb == 0) ps0 = acc; else ps1 = acc;
    }
    float ps = (q == 0) ? ps0 : ps1;
    if (c == 0) out[bbase + q] = total - ps;      // lanes 0 and 32 write
}

extern "C" void kernel_launch(void* const* d_in, const int* in_sizes, int n_in,
                              void* d_out, int out_size, void* d_ws, size_t ws_size,
                              hipStream_t stream) {
    const float* wtv   = (const float*)d_in[0];
    const float* trans = (const float*)d_in[1];
    const int*   rtag  = (const int*)d_in[2];
    (void)in_sizes; (void)n_in; (void)d_ws; (void)ws_size; (void)out_size;
    float* out = (float*)d_out;
    crf_kernel<<<256, 64, 0, stream>>>(wtv, trans, rtag, out);
}

// Round 4
// 139.092 us; speedup vs baseline: 1.3548x; 1.0420x over previous
//
#include <hip/hip_runtime.h>

// CRF loss on MI355X — staggered 2-phase pipeline, 2 batches per wave,
// with per-slot shadow-filled prefetch (round 4).
// B=512, L=512, T=32, S=34. Output f32[512].
//
// Same dataflow as round 3 (verified absmax 0.0): lanes 0-31 = batch b0,
// lanes 32-63 = b1, one state per lane; per step two slots:
//   slot O: publish bwd g_i + issue bwd reads | fwd FMA (reads from last slot)
//   slot E: publish fwd alpha_i + issue fwd reads | bwd FMA
// Round-4 changes (value-preserving):
//  - 16-step unrolled body; emission global-load (1/slot) and exp2 (1/slot)
//    moved INSIDE each slot after the read-issue barrier, so they fill the
//    LDS read-latency shadow instead of clumping serially at block top
//    (wave_barrier fences prevented the compiler from doing this itself).
//  - bwd publish value gB = stB*eoB precomputed in the previous slot's tail.
//  - rescale max-reduce via 4 DPP row_ror fmax + 1 ds_swizzle xor-16
//    (VALU-speed, replaces 5 dependent ds_bpermute round-trips).

#define F2   1.4426950408889634f   // log2(e)
#define LN2  0.6931471805599453f
#define BIAS 0.0078125f            // 2^-7, exact
#define BIASCNT 3577               // 7 * 511 applications of biased tc

__device__ __forceinline__ float grpmax32(float x) {
    // max over each 32-lane half: rotate-reduce within 16-lane DPP rows,
    // then xor-16 via ds_swizzle (stays inside each 32-lane group).
    int t;
    t = __builtin_amdgcn_update_dpp(__float_as_int(x), __float_as_int(x), 0x121, 0xf, 0xf, true);
    x = fmaxf(x, __int_as_float(t));   // row_ror:1
    t = __builtin_amdgcn_update_dpp(__float_as_int(x), __float_as_int(x), 0x122, 0xf, 0xf, true);
    x = fmaxf(x, __int_as_float(t));   // row_ror:2
    t = __builtin_amdgcn_update_dpp(__float_as_int(x), __float_as_int(x), 0x124, 0xf, 0xf, true);
    x = fmaxf(x, __int_as_float(t));   // row_ror:4
    t = __builtin_amdgcn_update_dpp(__float_as_int(x), __float_as_int(x), 0x128, 0xf, 0xf, true);
    x = fmaxf(x, __int_as_float(t));   // row_ror:8  -> per-16-row max
    t = __builtin_amdgcn_ds_swizzle(__float_as_int(x), 0x401F);  // xor 16
    x = fmaxf(x, __int_as_float(t));
    return x;
}

__global__ __launch_bounds__(64) void crf_kernel(
    const float* __restrict__ wtv,    // [512,512,32]
    const float* __restrict__ trans,  // [34,34]
    const int*   __restrict__ rtag,   // [512,512]
    float* __restrict__ out)          // [512]
{
    __shared__ __align__(16) float tlds[1156];  // raw translation (ln domain)
    __shared__ __align__(16) int   ltag[1024];  // gold tags, 2 batches
    __shared__ __align__(16) float alds[160];   // F: q*36+[0..31]; B: 80+q*36+[0..31]

    const int l = threadIdx.x;
    const int q = l >> 5;        // batch within pair
    const int c = l & 31;        // state-1
    const int bbase = blockIdx.x * 2;

    for (int k = l; k < 1156; k += 64) tlds[k] = trans[k];
    {
        const int* rtb = rtag + (size_t)bbase * 512;
        for (int k = l; k < 1024; k += 64) ltag[k] = rtb[k];
    }
    __syncthreads();  // once, before the main loop (graph-safe)

    // exp2-domain transitions, exact 2^-7 bias folded in
    float tcF[32], tcB[32];
    #pragma unroll
    for (int k = 0; k < 32; ++k) {
        tcF[k] = __builtin_exp2f(F2 * tlds[(k + 1) * 34 + (c + 1)]) * BIAS; // col c+1
        tcB[k] = __builtin_exp2f(F2 * tlds[(c + 1) * 34 + (k + 1)]) * BIAS; // row c+1
    }
    float aiF = __builtin_exp2f(F2 * tlds[c + 1]) * BIAS;  // START term, step 1 only

    const float* wbq = wtv + (size_t)(bbase + q) * (512 * 32);

    float stF = __builtin_exp2f(F2 * wbq[c]);   // alpha_0 (row-0 emission)
    float stB = 1.0f;                           // b_511
    int scF = 0, scB = 0;

    // emission pipeline: vn[j] holds raw value for step (body-local j);
    // refilled 8 steps ahead inside the slot shadows.
    float vnF[16], vnB[16];
    #pragma unroll
    for (int j = 0; j < 8; ++j) {
        vnF[j] = wbq[(1 + j) * 32 + c];        // rows 1..8
        vnB[j] = wbq[(511 - j) * 32 + c];      // rows 511..504
    }
    float eoF_c = __builtin_exp2f(F2 * vnF[0]);   // emission factor, step 1
    float gB    = stB * __builtin_exp2f(F2 * vnB[0]);  // bwd publish value, step 1

    float* aF = alds + q * 36;          // fwd region (16B-aligned, +4 banks/half)
    float* aB = alds + 80 + q * 36;     // bwd region
    const float4* f4 = (const float4*)aF;
    const float4* b4 = (const float4*)aB;

    float4 ra[8], rb[8];

    // ---- prologue: publish alpha_0, issue fwd reads ----
    aF[c] = stF;
    __builtin_amdgcn_wave_barrier();
    #pragma unroll
    for (int k = 0; k < 8; ++k) ra[k] = f4[k];
    __builtin_amdgcn_wave_barrier();

    for (int t0 = 1; t0 <= 241; t0 += 16) {   // 16 bodies x 16 steps = i = 1..256
        #pragma unroll
        for (int j = 0; j < 16; ++j) {
            const int i = t0 + j;

            // ---- SLOT O: publish bwd g_i, issue bwd reads | fwd FMA step i ----
            aB[c] = gB;
            __builtin_amdgcn_wave_barrier();
            #pragma unroll
            for (int k = 0; k < 8; ++k) rb[k] = b4[k];
            __builtin_amdgcn_wave_barrier();
            // shadow: bwd emission prefetch (row >= 248 at tail: in-bounds,
            // values unused past step 256) + next-step bwd emission factor
            vnB[(j + 8) & 15] = wbq[(512 - (i + 8)) * 32 + c];
            float eoB_n = __builtin_exp2f(F2 * vnB[(j + 1) & 15]);
            {
                float a0 = aiF, a1 = 0.0f, a2 = 0.0f, a3 = 0.0f;
                aiF = 0.0f;
                #pragma unroll
                for (int k = 0; k < 8; ++k) {
                    float4 x = ra[k];
                    a0 += x.x * tcF[4 * k + 0]; a1 += x.y * tcF[4 * k + 1];
                    a2 += x.z * tcF[4 * k + 2]; a3 += x.w * tcF[4 * k + 3];
                }
                float s = (a0 + a1) + (a2 + a3);
                stF = s * eoF_c;                  // fwd updates at all i = 1..256
            }
            if (j == 15) {
                // fwd rescale (every 16 steps) between update and publish
                float m = grpmax32(stF);
                int e = ((__float_as_int(m) >> 23) & 0xff) - 127;
                stF *= __int_as_float((127 - e) << 23);
                scF += e;
            }

            // ---- SLOT E: publish fwd alpha_i, issue fwd reads | bwd FMA step i ----
            aF[c] = stF;
            __builtin_amdgcn_wave_barrier();
            #pragma unroll
            for (int k = 0; k < 8; ++k) ra[k] = f4[k];
            __builtin_amdgcn_wave_barrier();
            // shadow: fwd emission prefetch (row <= 264 at tail: in-bounds,
            // unused) + next-step fwd emission factor
            vnF[(j + 8) & 15] = wbq[(i + 8) * 32 + c];
            float eoF_n = __builtin_exp2f(F2 * vnF[(j + 1) & 15]);
            {
                float a0 = 0.0f, a1 = 0.0f, a2 = 0.0f, a3 = 0.0f;
                #pragma unroll
                for (int k = 0; k < 8; ++k) {
                    float4 x = rb[k];
                    a0 += x.x * tcB[4 * k + 0]; a1 += x.y * tcB[4 * k + 1];
                    a2 += x.z * tcB[4 * k + 2]; a3 += x.w * tcB[4 * k + 3];
                }
                float s = (a0 + a1) + (a2 + a3);
                if (j == 15) stB = (t0 != 241) ? s : stB;  // i==256: fwd-only tail
                else         stB = s;
            }
            if (j == 15) {
                // bwd rescale at body end (before next publish)
                float m = grpmax32(stB);
                int e = ((__float_as_int(m) >> 23) & 0xff) - 127;
                stB *= __int_as_float((127 - e) << 23);
                scB += e;
            }
            gB   = stB * eoB_n;   // publish value for step i+1 (off write path)
            eoF_c = eoF_n;
        }
    }

    // ---- Z = sum_c af_256[c] * b_256[c], per 32-lane half ----
    float prod = stF * stB;
    prod += __shfl_xor(prod, 1);
    prod += __shfl_xor(prod, 2);
    prod += __shfl_xor(prod, 4);
    prod += __shfl_xor(prod, 8);
    prod += __shfl_xor(prod, 16);
    float total = ((float)(scF + scB + BIASCNT) + __builtin_log2f(prod)) * LN2;

    // ---- gold-path score epilogue: all 64 lanes per batch, gathers L2/L3-warm ----
    float ps0 = 0.0f, ps1 = 0.0f;
    #pragma unroll
    for (int bb = 0; bb < 2; ++bb) {
        const float* w  = wtv + (size_t)(bbase + bb) * (512 * 32);
        const int*   tg = ltag + (bb << 9);
        int   tcur[8];
        float em[8];
        #pragma unroll
        for (int k = 0; k < 8; ++k) tcur[k] = tg[l + 64 * k];
        #pragma unroll
        for (int k = 0; k < 8; ++k) em[k] = w[(l + 64 * k) * 32 + (tcur[k] - 1)];
        float acc = 0.0f;
        #pragma unroll
        for (int k = 0; k < 8; ++k) {
            int t  = l + 64 * k;
            int nx = tg[(t + 1) & 511];
            nx = (t == 511) ? 33 : nx;            // end term trans[tag_511][STOP]
            acc += em[k] + tlds[tcur[k] * 34 + nx];
        }
        if (l == 0) acc += tlds[tg[0]];           // start term trans[0][tag_0]
        acc += __shfl_xor(acc, 1);
        acc += __shfl_xor(acc, 2);
        acc += __shfl_xor(acc, 4);
        acc += __shfl_xor(acc, 8);
        acc += __shfl_xor(acc, 16);
        acc += __shfl_xor(acc, 32);
        if (bb == 0) ps0 = acc; else ps1 = acc;
    }
    float ps = (q == 0) ? ps0 : ps1;
    if (c == 0) out[bbase + q] = total - ps;      // lanes 0 and 32 write
}

extern "C" void kernel_launch(void* const* d_in, const int* in_sizes, int n_in,
                              void* d_out, int out_size, void* d_ws, size_t ws_size,
                              hipStream_t stream) {
    const float* wtv   = (const float*)d_in[0];
    const float* trans = (const float*)d_in[1];
    const int*   rtag  = (const int*)d_in[2];
    (void)in_sizes; (void)n_in; (void)d_ws; (void)ws_size; (void)out_size;
    float* out = (float*)d_out;
    crf_kernel<<<256, 64, 0, stream>>>(wtv, trans, rtag, out);
}